// Round 9
// baseline (868.526 us; speedup 1.0000x reference)
//
#include <hip/hip_runtime.h>
#include <hip/hip_bf16.h>

// Problem sizes (fixed)
#define BSZ  4096
#define TS   31
#define DIN  124
#define HH   256
#define FEA  64
#define VV   20
#define NCC  100

#define NGROUP 16          // groups
#define NRANK  16          // blocks per group (hidden slices)
#define GROWS  256         // batch rows per group

typedef __attribute__((ext_vector_type(8))) short bf16x8;   // 8 bf16 = 4 VGPR
typedef __attribute__((ext_vector_type(4))) float f32x4;

// ---- workspace layout (bytes) ----
#define OFF_WL0   0u          // 64 tiles x 12 kk x 1KB = 786432
#define OFF_WL1   786432u     // 64 tiles x 16 kk x 1KB = 1048576
#define OFF_WHD   1835008u    // 8 tiles x 8 kk x 1KB   = 65536
#define OFF_BG1   1900544u    // 1024 f32
#define OFF_BHD   1904640u    // 128 f32
#define OFF_SYNC  1905664u    // 16 groups x 64B counters
#define OFF_HBUF  2956288u    // 2 slots x 16 groups x 2 layers x 128KB (frag-packed)
#define HSLOT     4194304u    // one hbuf slot (4MB)
#define GBYTES    262144u     // per-group bytes in a slot
#define LBYTES    131072u     // per-layer bytes (16 rb x 8 kk x 1KB)

__device__ __forceinline__ unsigned short f2bf(float f) {
    unsigned int u = __float_as_uint(f);
    unsigned int r = (u + 0x7FFFu + ((u >> 16) & 1u)) >> 16;
    return (unsigned short)r;
}
__device__ __forceinline__ float sigmoidf_(float x) {
    return 1.f / (1.f + __expf(-x));
}
__device__ __forceinline__ float tanhf_(float x) {
    float ax = fabsf(x);
    float e = __expf(-2.f * ax);
    float t = (1.f - e) / (1.f + e);
    return copysignf(t, x);
}

// ---- device-coherent exchange ops: COMPILER-TRACKED scoped atomics ----
union U16B { unsigned long long u[2]; bf16x8 v; };
__device__ __forceinline__ bf16x8 ld16cc(const void* p) {
    U16B x;
    x.u[0] = __hip_atomic_load((const unsigned long long*)p,
                               __ATOMIC_RELAXED, __HIP_MEMORY_SCOPE_AGENT);
    x.u[1] = __hip_atomic_load((const unsigned long long*)((const char*)p + 8),
                               __ATOMIC_RELAXED, __HIP_MEMORY_SCOPE_AGENT);
    return x.v;
}
__device__ __forceinline__ void st_agent_u16(void* p, unsigned short v) {
    __hip_atomic_store((unsigned short*)p, v, __ATOMIC_RELAXED, __HIP_MEMORY_SCOPE_AGENT);
}

// ---------------------------------------------------------------------------
// Prep: pack weights into MFMA B-fragment blocks (lane l of frag (tile,kk)
// holds W[16*tile + (l&15)][kk*32 + (l>>4)*8 + j], j=0..7). Fuse biases.
// ---------------------------------------------------------------------------
__global__ __launch_bounds__(256) void prep_kernel(
    const float* __restrict__ Wih0, const float* __restrict__ Whh0,
    const float* __restrict__ bih0, const float* __restrict__ bhh0,
    const float* __restrict__ Wih1, const float* __restrict__ Whh1,
    const float* __restrict__ bih1, const float* __restrict__ bhh1,
    const float* __restrict__ Wout, const float* __restrict__ bout,
    const float* __restrict__ Wcv,  const float* __restrict__ bcv,
    char* __restrict__ ws)
{
    const int NFRAG = 64*12 + 64*16 + 8*8;      // 1856
    int u = blockIdx.x * 256 + threadIdx.x;
    if (u < NFRAG * 64) {
        int fb = u >> 6;
        int l  = u & 63;
        int r15 = l & 15, l4 = l >> 4;
        unsigned short tmp[8];
        int4* dst;
        if (fb < 768) {                          // layer 0: [Whh0 | Wih0 | bias]
            int tile = fb / 12, kk = fb - tile * 12;
            int row = tile * 16 + r15;
            int k0  = kk * 32 + l4 * 8;
            #pragma unroll
            for (int j = 0; j < 8; j++) {
                int k = k0 + j;
                float v;
                if (k < 256) v = Whh0[row * HH + k];
                else {
                    int kp = k - 256;
                    v = (kp < DIN) ? Wih0[row * DIN + kp]
                      : (kp == DIN ? bih0[row] + bhh0[row] : 0.f);
                }
                tmp[j] = f2bf(v);
            }
            dst = (int4*)(ws + OFF_WL0) + fb * 64 + l;
        } else if (fb < 1792) {                  // layer 1: [Wih1 | Whh1]
            int f = fb - 768;
            int tile = f >> 4, kk = f & 15;
            int row = tile * 16 + r15;
            int k0  = kk * 32 + l4 * 8;
            #pragma unroll
            for (int j = 0; j < 8; j++) {
                int k = k0 + j;
                float v = (k < 256) ? Wih1[row * HH + k] : Whh1[row * HH + k - 256];
                tmp[j] = f2bf(v);
            }
            dst = (int4*)(ws + OFF_WL1) + f * 64 + l;
        } else {                                 // head: [Wout | Wcv | 0]
            int f = fb - 1792;
            int tile = f >> 3, kk = f & 7;
            int row = tile * 16 + r15;
            int k0  = kk * 32 + l4 * 8;
            #pragma unroll
            for (int j = 0; j < 8; j++) {
                int k = k0 + j;
                float v = (row < VV) ? Wout[row * HH + k]
                        : (row < VV + NCC ? Wcv[(row - VV) * HH + k] : 0.f);
                tmp[j] = f2bf(v);
            }
            dst = (int4*)(ws + OFF_WHD) + f * 64 + l;
        }
        *dst = *(const int4*)tmp;
    } else if (u < NFRAG * 64 + 1024) {
        int g = u - NFRAG * 64;
        ((float*)(ws + OFF_BG1))[g] = bih1[g] + bhh1[g];
    } else if (u < NFRAG * 64 + 1024 + 128) {
        int v = u - NFRAG * 64 - 1024;
        float b = (v < VV) ? bout[v] : (v < VV + NCC ? bcv[v - VV] : 0.f);
        ((float*)(ws + OFF_BHD))[v] = b;
    }
}

// ---------------------------------------------------------------------------
// group sync, fence-free: exchange data moves via agent-coherent atomics.
// ---------------------------------------------------------------------------
__device__ __forceinline__ void g_arrive(unsigned* cnt) {
    asm volatile("s_waitcnt vmcnt(0)" ::: "memory");   // no outputs: safe asm
    __syncthreads();
    if (threadIdx.x == 0)
        __hip_atomic_fetch_add(cnt, 1u, __ATOMIC_RELAXED, __HIP_MEMORY_SCOPE_AGENT);
}
__device__ __forceinline__ void g_wait(unsigned* cnt, unsigned target) {
    if (threadIdx.x == 0) {
        while (__hip_atomic_load(cnt, __ATOMIC_RELAXED, __HIP_MEMORY_SCOPE_AGENT) < target)
            __builtin_amdgcn_s_sleep(2);
    }
    __syncthreads();
    __builtin_amdgcn_sched_barrier(0);
}

// ---------------------------------------------------------------------------
// Main: grid = 256 (1/CU). g = bid&15, rank = bid>>4 owns hidden slice
// [16*rank,16*rank+16), weights in LDS. 512 threads (8 waves); wave w handles
// group rows [32w,32w+32) for L0/L1, head col-tile w, softmax rows {2w,2w+1}.
// h-exchange frag-packed per group (coalesced 16B/lane). Head A-rows come via
// LDS broadcast from wave rank>>1's a1 (they coincide) — no extra LLC loads.
// Epoch e: L0(t=e) [a1 issued early], L1(t=e-1), broadcast, arrive,
// head+softmax(t=e-2) overlaps poll, wait.
// ---------------------------------------------------------------------------
__global__ __launch_bounds__(512, 1) void lstm_main(
    const float* __restrict__ x,        // [4096,64]
    const int*   __restrict__ choices,  // [4096,31]
    const int*   __restrict__ masks,    // [4096,31,20]
    const int*   __restrict__ c_idx,    // [4096,31]
    const int*   __restrict__ c_choice, // [4096,31]
    const float* __restrict__ Wxc,      // [256,64]
    const float* __restrict__ bxc,      // [256]
    char* __restrict__ ws,
    float* __restrict__ out)            // [4096]
{
    const int tid  = threadIdx.x;
    const int w    = tid >> 6;          // wave 0..7
    const int lane = tid & 63;
    const int l15  = lane & 15;
    const int l4   = lane >> 4;         // 0..3
    const int g    = blockIdx.x & 15;   // group
    const int rank = blockIdx.x >> 4;   // hidden slice

    __shared__ int4 ldsL0[4][12][64];   // 48KB
    __shared__ int4 ldsL1[4][16][64];   // 64KB
    __shared__ int4 ldsHDbuf[8][64];    // 8KB: head A-rows broadcast
    __shared__ float headbuf[16][132];  // f32 logits for own 16 rows
    __shared__ int choices_lds[16][TS];
    __shared__ int cidx_lds[16][TS];
    __shared__ int cch_lds[16][TS];

    const int obase = g * GROWS + 16 * rank;      // own softmax rows base
    const int arow0 = g * GROWS + 32 * w + l15;   // global A row (for xb packing)

    // ---- load weight slices into LDS ----
    {
        const int4* src = (const int4*)(ws + OFF_WL0);
        for (int i = tid; i < 4 * 12 * 64; i += 512) {
            int gt = i / 768, r = i - gt * 768;
            ((int4*)ldsL0)[i] = src[((gt * 16 + rank) * 12) * 64 + r];
        }
        src = (const int4*)(ws + OFF_WL1);
        for (int i = tid; i < 4 * 16 * 64; i += 512) {
            int gt = i / 1024, r = i - gt * 1024;
            ((int4*)ldsL1)[i] = src[((gt * 16 + rank) * 16) * 64 + r];
        }
    }
    // head weight col-tile w in registers (persistent)
    bf16x8 whd[8];
    #pragma unroll
    for (int kk = 0; kk < 8; kk++)
        whd[kk] = *(const bf16x8*)(ws + OFF_WHD + ((size_t)(w * 8 + kk) * 64 + lane) * 16);

    // ---- bit-pack x-bits for this thread's two A-rows into registers ----
    unsigned xb[2][4];
    #pragma unroll
    for (int rg = 0; rg < 2; rg++) {
        xb[rg][0] = 0; xb[rg][1] = 0; xb[rg][2] = 0; xb[rg][3] = 0;
        const int rr = arow0 + 16 * rg;
        #pragma unroll
        for (int t = 0; t < TS; t++) {
            int ch = choices[rr * TS + t];
            #pragma unroll
            for (int i = 0; i < 4; i++) {
                const int col = 4 * t + i;
                if ((ch >> (3 - i)) & 1) xb[rg][col >> 5] |= (1u << (col & 31));
            }
        }
        xb[rg][3] |= (1u << 28);                 // col 124 = 1.0 (bias slot)
    }

    // ---- preload per-row scalars into LDS ----
    for (int i = tid; i < 16 * TS; i += 512) {
        int r = i / TS, tt = i - r * TS;
        choices_lds[r][tt] = choices[(obase + r) * TS + tt];
        cidx_lds[r][tt]    = c_idx[(obase + r) * TS + tt];
        cch_lds[r][tt]     = c_choice[(obase + r) * TS + tt];
    }

    // ---- c0 = x @ Wxc.T + bxc ----
    float c0r[2][4], c1r[2][4];
    {
        const int unit = 16 * rank + l15;
        float acc[2][4] = {{0.f,0.f,0.f,0.f},{0.f,0.f,0.f,0.f}};
        #pragma unroll 4
        for (int k4 = 0; k4 < 16; k4++) {
            float4 wv = *(const float4*)(Wxc + unit * FEA + k4 * 4);
            #pragma unroll
            for (int rg = 0; rg < 2; rg++)
                #pragma unroll
                for (int q = 0; q < 4; q++) {
                    int row = g * GROWS + 32 * w + 16 * rg + l4 * 4 + q;
                    float4 xv = *(const float4*)(x + row * FEA + k4 * 4);
                    acc[rg][q] += wv.x*xv.x + wv.y*xv.y + wv.z*xv.z + wv.w*xv.w;
                }
        }
        float bb = bxc[unit];
        #pragma unroll
        for (int rg = 0; rg < 2; rg++)
            #pragma unroll
            for (int q = 0; q < 4; q++) { c0r[rg][q] = acc[rg][q] + bb; c1r[rg][q] = acc[rg][q] + bb; }
    }

    // hoisted biases
    float bb1[4], bbHD;
    {
        const float* bg1 = (const float*)(ws + OFF_BG1);
        #pragma unroll
        for (int gt = 0; gt < 4; gt++) bb1[gt] = bg1[(gt * 16 + rank) * 16 + l15];
        bbHD = ((const float*)(ws + OFF_BHD))[w * 16 + l15];
    }

    // ---- frag-packed exchange address bases ----
    const unsigned rd_base = (unsigned)(2 * w * 8) * 1024u + (unsigned)lane * 16u;
    const unsigned hd_base = LBYTES + (unsigned)(rank * 8) * 1024u + (unsigned)lane * 16u;
    const unsigned scon = (2u * (unsigned)rank + (unsigned)(l15 >> 3)) & 3u;
    const unsigned st_base = ((unsigned)(2 * w * 8) + (unsigned)(rank >> 1)) * 1024u
                           + scon * 256u + (unsigned)(l4 * 4) * 16u
                           + 2u * (unsigned)(l15 & 7);

    unsigned* cnt = (unsigned*)(ws + OFF_SYNC) + g * 16;
    unsigned tgt = NRANK;
    float lp = 0.f;
    const int half = lane >> 5, ln = lane & 31;
    const int srow = 2 * w + half;                // own softmax row (0..15)
    const int hw   = rank >> 1;                   // wave that owns head A-rows
    const int hrg  = rank & 1;

    __syncthreads();

    for (int e = 0; e <= 32; e++) {
        const char* gb_prev = ws + OFF_HBUF + (size_t)((unsigned)(e + 1) & 1u) * HSLOT + (size_t)g * GBYTES;
        char*       gb_cur  = (char*)(ws + OFF_HBUF + (size_t)((unsigned)e & 1u) * HSLOT + (size_t)g * GBYTES);
        const bool doL0 = (e < TS);
        const bool doL1 = (e >= 1 && e <= TS);
        const bool doHD = (e >= 2);
        const int  tH   = e - 2;

        // ---- h0(e-1) fragments (shared by L0 and L1): coalesced 16B/lane ----
        bf16x8 a0[2][8];
        if (doL0 || doL1) {
            #pragma unroll
            for (int rg = 0; rg < 2; rg++) {
                const char* ar = gb_prev + rd_base + rg * 8192u;
                #pragma unroll
                for (int kk = 0; kk < 8; kk++) a0[rg][kk] = ld16cc(ar + kk * 1024u);
            }
        }
        // ---- issue h1(e-2) volley EARLY: latency hides under L0 compute ----
        bf16x8 a1[2][8];
        if (doL1) {
            #pragma unroll
            for (int rg = 0; rg < 2; rg++) {
                const char* ar = gb_prev + LBYTES + rd_base + rg * 8192u;
                #pragma unroll
                for (int kk = 0; kk < 8; kk++) a1[rg][kk] = ld16cc(ar + kk * 1024u);
            }
        }

        // ---- L0(t=e): K = [h0(e-1) | xbits(<=e) | 1] ----
        if (doL0) {
            bf16x8 ax[2][4];
            #pragma unroll
            for (int rg = 0; rg < 2; rg++)
                #pragma unroll
                for (int kk = 0; kk < 4; kk++)
                    #pragma unroll
                    for (int j = 0; j < 8; j++) {
                        const int cj = l4 * 8 + j;
                        int col = kk * 32 + cj;
                        bool take = (col < 4 * e) || (col == 124);
                        bool bit  = (xb[rg][kk] >> (col & 31)) & 1u;
                        ax[rg][kk][j] = (take && bit) ? (short)0x3F80 : (short)0;
                    }

            f32x4 acc0[2][4];
            #pragma unroll
            for (int rg = 0; rg < 2; rg++)
                #pragma unroll
                for (int gt = 0; gt < 4; gt++) { f32x4 z; z[0]=z[1]=z[2]=z[3]=0.f; acc0[rg][gt] = z; }
            #pragma unroll
            for (int kk = 0; kk < 12; kk++) {
                bf16x8 b0 = *(const bf16x8*)&ldsL0[0][kk][lane];
                bf16x8 b1 = *(const bf16x8*)&ldsL0[1][kk][lane];
                bf16x8 b2 = *(const bf16x8*)&ldsL0[2][kk][lane];
                bf16x8 b3 = *(const bf16x8*)&ldsL0[3][kk][lane];
                bf16x8 va0 = (kk < 8) ? a0[0][kk] : ax[0][kk - 8];
                bf16x8 va1 = (kk < 8) ? a0[1][kk] : ax[1][kk - 8];
                acc0[0][0] = __builtin_amdgcn_mfma_f32_16x16x32_bf16(va0, b0, acc0[0][0], 0, 0, 0);
                acc0[1][0] = __builtin_amdgcn_mfma_f32_16x16x32_bf16(va1, b0, acc0[1][0], 0, 0, 0);
                acc0[0][1] = __builtin_amdgcn_mfma_f32_16x16x32_bf16(va0, b1, acc0[0][1], 0, 0, 0);
                acc0[1][1] = __builtin_amdgcn_mfma_f32_16x16x32_bf16(va1, b1, acc0[1][1], 0, 0, 0);
                acc0[0][2] = __builtin_amdgcn_mfma_f32_16x16x32_bf16(va0, b2, acc0[0][2], 0, 0, 0);
                acc0[1][2] = __builtin_amdgcn_mfma_f32_16x16x32_bf16(va1, b2, acc0[1][2], 0, 0, 0);
                acc0[0][3] = __builtin_amdgcn_mfma_f32_16x16x32_bf16(va0, b3, acc0[0][3], 0, 0, 0);
                acc0[1][3] = __builtin_amdgcn_mfma_f32_16x16x32_bf16(va1, b3, acc0[1][3], 0, 0, 0);
            }
            #pragma unroll
            for (int rg = 0; rg < 2; rg++)
                #pragma unroll
                for (int q = 0; q < 4; q++) {
                    float iv = sigmoidf_(acc0[rg][0][q]);
                    float fv = sigmoidf_(acc0[rg][1][q]);
                    float gv = tanhf_(acc0[rg][2][q]);
                    float ov = sigmoidf_(acc0[rg][3][q]);
                    float cn = fv * c0r[rg][q] + iv * gv;
                    c0r[rg][q] = cn;
                    st_agent_u16(gb_cur + st_base + rg * 8192u + q * 16u,
                                 f2bf(ov * tanhf_(cn)));
                }
        }

        // ---- L1(t=e-1): K = [h0(e-1) | h1(e-2)] ----
        if (doL1) {
            f32x4 acc1[2][4];
            #pragma unroll
            for (int rg = 0; rg < 2; rg++)
                #pragma unroll
                for (int gt = 0; gt < 4; gt++) { f32x4 z; z[0]=z[1]=z[2]=z[3]=bb1[gt]; acc1[rg][gt] = z; }
            #pragma unroll
            for (int kk = 0; kk < 16; kk++) {
                bf16x8 b0 = *(const bf16x8*)&ldsL1[0][kk][lane];
                bf16x8 b1 = *(const bf16x8*)&ldsL1[1][kk][lane];
                bf16x8 b2 = *(const bf16x8*)&ldsL1[2][kk][lane];
                bf16x8 b3 = *(const bf16x8*)&ldsL1[3][kk][lane];
                bf16x8 va0 = (kk < 8) ? a0[0][kk] : a1[0][kk - 8];
                bf16x8 va1 = (kk < 8) ? a0[1][kk] : a1[1][kk - 8];
                acc1[0][0] = __builtin_amdgcn_mfma_f32_16x16x32_bf16(va0, b0, acc1[0][0], 0, 0, 0);
                acc1[1][0] = __builtin_amdgcn_mfma_f32_16x16x32_bf16(va1, b0, acc1[1][0], 0, 0, 0);
                acc1[0][1] = __builtin_amdgcn_mfma_f32_16x16x32_bf16(va0, b1, acc1[0][1], 0, 0, 0);
                acc1[1][1] = __builtin_amdgcn_mfma_f32_16x16x32_bf16(va1, b1, acc1[1][1], 0, 0, 0);
                acc1[0][2] = __builtin_amdgcn_mfma_f32_16x16x32_bf16(va0, b2, acc1[0][2], 0, 0, 0);
                acc1[1][2] = __builtin_amdgcn_mfma_f32_16x16x32_bf16(va1, b2, acc1[1][2], 0, 0, 0);
                acc1[0][3] = __builtin_amdgcn_mfma_f32_16x16x32_bf16(va0, b3, acc1[0][3], 0, 0, 0);
                acc1[1][3] = __builtin_amdgcn_mfma_f32_16x16x32_bf16(va1, b3, acc1[1][3], 0, 0, 0);
            }
            #pragma unroll
            for (int rg = 0; rg < 2; rg++)
                #pragma unroll
                for (int q = 0; q < 4; q++) {
                    float iv = sigmoidf_(acc1[rg][0][q]);
                    float fv = sigmoidf_(acc1[rg][1][q]);
                    float gv = tanhf_(acc1[rg][2][q]);
                    float ov = sigmoidf_(acc1[rg][3][q]);
                    float cn = fv * c1r[rg][q] + iv * gv;
                    c1r[rg][q] = cn;
                    st_agent_u16(gb_cur + LBYTES + st_base + rg * 8192u + q * 16u,
                                 f2bf(ov * tanhf_(cn)));
                }
            // broadcast head A-rows (h1(e-2), rows of this block's rank) to LDS.
            // Visible to all waves after g_arrive's __syncthreads.
            if (w == hw) {
                #pragma unroll
                for (int kk = 0; kk < 8; kk++)
                    ldsHDbuf[kk][lane] = (hrg == 0) ? *(const int4*)&a1[0][kk]
                                                    : *(const int4*)&a1[1][kk];
            }
        }

        if (e <= 31) g_arrive(cnt);

        // ---- head+softmax (t=e-2 data) overlaps other blocks' progress ----
        if (doHD) {
            bf16x8 ahd[8];
            if (e <= TS) {                        // broadcast path (after barrier)
                #pragma unroll
                for (int kk = 0; kk < 8; kk++)
                    ahd[kk] = *(const bf16x8*)&ldsHDbuf[kk][lane];
            } else {                              // e == 32 tail: direct loads
                const char* ar = gb_prev + hd_base;
                #pragma unroll
                for (int kk = 0; kk < 8; kk++) ahd[kk] = ld16cc(ar + kk * 1024u);
            }
            f32x4 hc; hc[0] = bbHD; hc[1] = bbHD; hc[2] = bbHD; hc[3] = bbHD;
            #pragma unroll
            for (int kk = 0; kk < 8; kk++)
                hc = __builtin_amdgcn_mfma_f32_16x16x32_bf16(ahd[kk], whd[kk], hc, 0, 0, 0);
            #pragma unroll
            for (int q = 0; q < 4; q++)
                headbuf[l4 * 4 + q][w * 16 + l15] = hc[q];
            __syncthreads();

            const int sr = obase + srow;
            float4 v4 = *(const float4*)&headbuf[srow][4 * ln];
            const float NINF = -__builtin_inff();

            // token softmax over cols 0..19 (masked)
            float t0 = NINF, t1 = NINF, t2 = NINF, t3 = NINF;
            if (ln < 5) {
                const int4 mk = *(const int4*)(masks + ((size_t)sr * TS + tH) * VV + 4 * ln);
                t0 = mk.x ? v4.x : -1e9f;
                t1 = mk.y ? v4.y : -1e9f;
                t2 = mk.z ? v4.z : -1e9f;
                t3 = mk.w ? v4.w : -1e9f;
            }
            float m = fmaxf(fmaxf(t0, t1), fmaxf(t2, t3));
            #pragma unroll
            for (int off = 16; off; off >>= 1) m = fmaxf(m, __shfl_xor(m, off));
            float ee = (ln < 5) ? (__expf(t0 - m) + __expf(t1 - m) + __expf(t2 - m) + __expf(t3 - m)) : 0.f;
            #pragma unroll
            for (int off = 16; off; off >>= 1) ee += __shfl_xor(ee, off);
            float lse = m + __logf(ee);
            int ch = choices_lds[srow][tH];
            int cm = ch & 3;
            float chsel = (cm == 0) ? t0 : (cm == 1) ? t1 : (cm == 2) ? t2 : t3;
            float chlog = __shfl(chsel, (ch >> 2) + (half << 5));
            float lpadd = chlog - lse;

            // class softmax over cols 20..119
            const bool a2 = (ln >= 5) && (ln < 30);
            float u0 = a2 ? v4.x : NINF, u1 = a2 ? v4.y : NINF;
            float u2 = a2 ? v4.z : NINF, u3 = a2 ? v4.w : NINF;
            float mc = fmaxf(fmaxf(u0, u1), fmaxf(u2, u3));
            #pragma unroll
            for (int off = 16; off; off >>= 1) mc = fmaxf(mc, __shfl_xor(mc, off));
            float ec = a2 ? (__expf(u0 - mc) + __expf(u1 - mc) + __expf(u2 - mc) + __expf(u3 - mc)) : 0.f;
            #pragma unroll
            for (int off = 16; off; off >>= 1) ec += __shfl_xor(ec, off);
            float lsec = mc + __logf(ec);
            int ci = cidx_lds[srow][tH];
            if (ci) {
                int col2 = VV + cch_lds[srow][tH];
                int sm = col2 & 3;
                float cand = (sm == 0) ? u0 : (sm == 1) ? u1 : (sm == 2) ? u2 : u3;
                float clog = __shfl(cand, (col2 >> 2) + (half << 5));
                lpadd += clog - lsec;
            }
            lp += lpadd;
        }

        if (e <= 31) { g_wait(cnt, tgt); tgt += NRANK; }
    }

    if (ln == 0) out[obase + srow] = lp;
}

extern "C" void kernel_launch(void* const* d_in, const int* in_sizes, int n_in,
                              void* d_out, int out_size, void* d_ws, size_t ws_size,
                              hipStream_t stream) {
    const float* x        = (const float*)d_in[0];
    const int*   choices  = (const int*)d_in[1];
    const int*   masks    = (const int*)d_in[2];
    const int*   c_idx    = (const int*)d_in[3];
    const int*   c_choice = (const int*)d_in[4];
    const float* Wih0 = (const float*)d_in[5];
    const float* Whh0 = (const float*)d_in[6];
    const float* bih0 = (const float*)d_in[7];
    const float* bhh0 = (const float*)d_in[8];
    const float* Wih1 = (const float*)d_in[9];
    const float* Whh1 = (const float*)d_in[10];
    const float* bih1 = (const float*)d_in[11];
    const float* bhh1 = (const float*)d_in[12];
    const float* Wout = (const float*)d_in[13];
    const float* bout = (const float*)d_in[14];
    const float* Wxc  = (const float*)d_in[15];
    const float* bxc  = (const float*)d_in[16];
    const float* Wcv  = (const float*)d_in[17];
    const float* bcv  = (const float*)d_in[18];
    char* ws = (char*)d_ws;

    hipMemsetAsync(ws + OFF_SYNC, 0, 1024, stream);
    hipMemsetAsync(ws + OFF_HBUF, 0, 2 * HSLOT, stream);

    hipLaunchKernelGGL(prep_kernel, dim3(469), dim3(256), 0, stream,
                       Wih0, Whh0, bih0, bhh0, Wih1, Whh1, bih1, bhh1,
                       Wout, bout, Wcv, bcv, ws);
    hipLaunchKernelGGL(lstm_main, dim3(256), dim3(512), 0, stream,
                       x, choices, masks, c_idx, c_choice,
                       Wxc, bxc, ws, (float*)d_out);
}